// Round 11
// baseline (301.657 us; speedup 1.0000x reference)
//
#include <hip/hip_runtime.h>
#include <stdint.h>

typedef __attribute__((ext_vector_type(8))) __bf16 bf16x8;
typedef __attribute__((ext_vector_type(4))) float f32x4;

__device__ inline unsigned short f32_to_bf16_rne(float f) {
  union { float f; uint32_t u; } c; c.f = f;
  uint32_t u = c.u;
  uint32_t r = (u + 0x7FFFu + ((u >> 16) & 1u)) >> 16;
  return (unsigned short)r;
}

// ---------- pass 1: x (f32) -> A (bf16 bits) ----------
__global__ __launch_bounds__(256) void convert_x_kernel(const float* __restrict__ X,
                                                        unsigned short* __restrict__ A,
                                                        size_t n) {
  size_t i = (size_t)blockIdx.x * 256 + threadIdx.x;
  size_t stride = (size_t)gridDim.x * 256;
  for (size_t e = i * 4; e < n; e += stride * 4) {
    const float4 v = *reinterpret_cast<const float4*>(X + e);
    ushort4 o;
    o.x = f32_to_bf16_rne(v.x);
    o.y = f32_to_bf16_rne(v.y);
    o.z = f32_to_bf16_rne(v.z);
    o.w = f32_to_bf16_rne(v.w);
    *reinterpret_cast<ushort4*>(A + e) = o;
  }
}

// ---------- pass 2: Bt[n][k] = sign(Km[k][n]) as bf16 (+1/-1 exact) ----------
__global__ __launch_bounds__(256) void sign_transpose_kernel(const float* __restrict__ Km,
                                                             unsigned short* __restrict__ Bt,
                                                             int K, int N) {
  __shared__ unsigned short tile[64][65];
  const int k0 = blockIdx.x * 64;
  const int n0 = blockIdx.y * 64;
  const int t = threadIdx.x;
#pragma unroll
  for (int i = 0; i < 16; ++i) {
    int idx = t + i * 256;
    int kk = idx >> 6, nn = idx & 63;
    float v = Km[(size_t)(k0 + kk) * N + (n0 + nn)];
    tile[kk][nn] = (v >= 0.0f) ? (unsigned short)0x3F80u : (unsigned short)0xBF80u;
  }
  __syncthreads();
#pragma unroll
  for (int i = 0; i < 16; ++i) {
    int idx = t + i * 256;
    int nn = idx >> 6, kk = idx & 63;
    Bt[(size_t)(n0 + nn) * K + (k0 + kk)] = tile[kk][nn];
  }
}

// ---------- pass 3: 128x256-tile bf16 GEMM, 2 blocks/CU (desync) ----------
// A: [M][K] bf16 row-major; Bt: [N][K] bf16 row-major; C: [M][N] f32.
// 256 threads = 4 waves (wc=0..3); wave output 128x64 via 8x4 16x16 frags
// (identical fragment/epilogue code to r4-r10, wr==0). BK=32 K-tiles in a
// ring-3 LDS buffer (3 x 24 KiB = 72 KiB) -> TWO blocks co-resident per CU
// (144 <= 160 KiB). The two blocks barrier INDEPENDENTLY -> when one is in
// its read/stage window the other's MFMA clusters feed the SIMDs (m114:
// cross-wave MFMA/VALU overlap is free). This attacks the ~52% MfmaUtil
// lockstep ceiling measured identically across r4/r7/r8/r10 schedules.
//
// LEDGER (ring-3, stage t+2, vmcnt(0)+barrier per iter):
//  RAW: at entry of iter t, vmcnt(0)+barrier at end of t-1 => ALL stages
//    issued through iter t-1 are landed block-wide = tiles <= t+1. Iter t
//    reads tile t (af1, buf cb) and tile t+1 (preloads, buf nb). Safe.
//  WAR: iter t stages tile t+2 into buf (t+2)%3 = (t-1)%3 = tile t-1's buf;
//    its last reads (af1 of iter t-1, preloads of iter t-2) are lgkm-drained
//    before their consuming MFMAs in iter t-1, which precede the end-of-
//    (t-1) barrier < iter t's stage issues. Safe.
//  vmcnt(0) stall risk: it drains only loads issued EARLIER IN THE SAME
//    iter (~1000+ cyc before the wait; Bt/A panels L2-hot) -> minimal.
//  Tail: ts clamps to NT-1 (re-stages identical bytes into the rotating
//    target; landed before any read via the same vmcnt(0); values benign).
// T2 swizzle: row = 64 B = 4 slots of 16 B; slot ^= (row>>1)&3 (2-way free,
// 0 conflicts measured r4-r10). gl_lds dest linear; global source slot
// pre-swizzled (rule 21).

template <int NISS>
__device__ __forceinline__ void stage_rows(const unsigned short* __restrict__ G,
                                           size_t grow0, int K, int k0,
                                           unsigned short* lds_base,  // block-uniform
                                           int tid) {
#pragma unroll
  for (int i = 0; i < NISS; ++i) {
    const int row = i * 64 + (tid >> 2);               // 64 rows per issue
    const int srcslot = (tid & 3) ^ ((row >> 1) & 3);  // pre-swizzled source
    const unsigned short* ga = G + (grow0 + row) * (size_t)K + k0 + srcslot * 8;
    __builtin_amdgcn_global_load_lds(
        (const __attribute__((address_space(1))) void*)ga,
        (__attribute__((address_space(3))) void*)(lds_base + i * 2048 + (tid >> 6) * 512),
        16, 0, 0);
  }
}

#define MFMA8(ACCR, AFRAG, BFRAG, I0, I1)                                             \
  __builtin_amdgcn_s_setprio(1);                                                      \
  _Pragma("unroll")                                                                   \
  for (int mi = (I0); mi < (I1); ++mi)                                                \
    _Pragma("unroll")                                                                 \
    for (int ni = 0; ni < 4; ++ni)                                                    \
      acc[(ACCR) + mi][ni] = __builtin_amdgcn_mfma_f32_16x16x32_bf16(                 \
          AFRAG[mi], BFRAG[ni], acc[(ACCR) + mi][ni], 0, 0, 0);                       \
  __builtin_amdgcn_s_setprio(0);                                                      \
  __builtin_amdgcn_sched_barrier(0);

// One iteration. CBo/NBo/TBo: short-offsets of current/next/stage-target
// ring bufs. AFC/BFC in regs; AFN/BFN receive next iter's cluster-0 operands.
#define GEMM_ITER(T, CBo, NBo, TBo, AFC, BFC, AFN, BFN)                               \
  {                                                                                   \
    const int ts = ((T) + 2 < NTt) ? ((T) + 2) : (NTt - 1);                           \
    bf16x8 af1[4];                                                                    \
    _Pragma("unroll")                                                                 \
    for (int mi = 0; mi < 4; ++mi)                                                    \
      af1[mi] = *reinterpret_cast<const bf16x8*>(&lds[(CBo) + aoff + 2048 + mi * 512]); \
    stage_rows<2>(A, a_row0, K, ts * 32, (unsigned short*)lds + (TBo), tid);          \
    __builtin_amdgcn_sched_barrier(0);                                                \
    MFMA8(0, AFC, BFC, 0, 2)                                                          \
    _Pragma("unroll")                                                                 \
    for (int ni = 0; ni < 2; ++ni)                                                    \
      BFN[ni] = *reinterpret_cast<const bf16x8*>(&lds[(NBo) + boff + ni * 512]);      \
    __builtin_amdgcn_sched_barrier(0);                                                \
    MFMA8(0, AFC, BFC, 2, 4)                                                          \
    _Pragma("unroll")                                                                 \
    for (int ni = 2; ni < 4; ++ni)                                                    \
      BFN[ni] = *reinterpret_cast<const bf16x8*>(&lds[(NBo) + boff + ni * 512]);      \
    _Pragma("unroll")                                                                 \
    for (int mi = 0; mi < 2; ++mi)                                                    \
      AFN[mi] = *reinterpret_cast<const bf16x8*>(&lds[(NBo) + aoff + mi * 512]);      \
    stage_rows<4>(Bt, b_row0, K, ts * 32, (unsigned short*)lds + (TBo) + 4096, tid);  \
    __builtin_amdgcn_sched_barrier(0);                                                \
    MFMA8(4, af1, BFC, 0, 2)                                                          \
    _Pragma("unroll")                                                                 \
    for (int mi = 2; mi < 4; ++mi)                                                    \
      AFN[mi] = *reinterpret_cast<const bf16x8*>(&lds[(NBo) + aoff + mi * 512]);      \
    __builtin_amdgcn_sched_barrier(0);                                                \
    MFMA8(4, af1, BFC, 2, 4)                                                          \
    asm volatile("s_waitcnt vmcnt(0)\n" ::: "memory");                                \
    __builtin_amdgcn_s_barrier();                                                     \
  }

__global__ __launch_bounds__(256, 2) void gemm_bf16_128x256(const unsigned short* __restrict__ A,
                                                            const unsigned short* __restrict__ Bt,
                                                            float* __restrict__ C,
                                                            int M, int N, int K) {
  // ring-3 bufs of 12288 shorts: A[128][32] @ +0 (4096), B[256][32] @ +4096 (8192)
  __shared__ unsigned short lds[3 * 12288];  // 72 KiB -> 2 blocks/CU

  const int nBN = N >> 8;  // 256-col panels
  const int nwg = gridDim.x;
  const int bid = blockIdx.x;
  int swz = bid;
  if ((nwg & 7) == 0) {  // bijective XCD swizzle
    const int q = nwg >> 3;
    swz = (bid & 7) * q + (bid >> 3);
  }
  const size_t a_row0 = (size_t)(swz / nBN) * 128;
  const size_t b_row0 = (size_t)(swz % nBN) * 256;

  const int tid = threadIdx.x;
  const int wv = tid >> 6, ln = tid & 63;
  const int llo = ln & 15, lhi = ln >> 4;
  const int wc = wv;                       // 4 waves across 256 cols
  const int sA = lhi ^ ((llo >> 1) & 3);   // swizzled 16B-slot for ds_read

  // per-lane ds_read bases (shorts, relative to buf start)
  const int aoff = llo * 32 + sA * 8;                    // + mi*512 (mi 0..7)
  const int boff = 4096 + (wc * 64 + llo) * 32 + sA * 8; // + ni*512 (ni 0..3)

  const int NTt = K >> 5;  // K-tiles (even; launch guards K%128==0)

  f32x4 acc[8][4];
#pragma unroll
  for (int i = 0; i < 8; ++i)
#pragma unroll
    for (int j = 0; j < 4; ++j) acc[i][j] = (f32x4){0.f, 0.f, 0.f, 0.f};

  // ---- prologue: stage tiles 0,1; drain; preload tile-0 cluster-0 ----
  stage_rows<2>(A, a_row0, K, 0, (unsigned short*)lds, tid);
  stage_rows<4>(Bt, b_row0, K, 0, (unsigned short*)lds + 4096, tid);
  stage_rows<2>(A, a_row0, K, 32, (unsigned short*)lds + 12288, tid);
  stage_rows<4>(Bt, b_row0, K, 32, (unsigned short*)lds + 12288 + 4096, tid);
  asm volatile("s_waitcnt vmcnt(0)\n" ::: "memory");
  __builtin_amdgcn_s_barrier();

  bf16x8 af0_a[4], bfr_a[4], af0_b[4], bfr_b[4];
#pragma unroll
  for (int ni = 0; ni < 4; ++ni)
    bfr_a[ni] = *reinterpret_cast<const bf16x8*>(&lds[boff + ni * 512]);
#pragma unroll
  for (int mi = 0; mi < 4; ++mi)
    af0_a[mi] = *reinterpret_cast<const bf16x8*>(&lds[aoff + mi * 512]);

  // ---- main loop: ring-3 rotation + reg ping-pong (NTt even) ----
  int cb = 0, nb2 = 12288, tb = 24576;
  for (int t = 0; t < NTt; t += 2) {
    GEMM_ITER(t, cb, nb2, tb, af0_a, bfr_a, af0_b, bfr_b)
    { int tmp = cb; cb = nb2; nb2 = tb; tb = tmp; }
    GEMM_ITER(t + 1, cb, nb2, tb, af0_b, bfr_b, af0_a, bfr_a)
    { int tmp = cb; cb = nb2; nb2 = tb; tb = tmp; }
  }

  // ---- epilogue: C/D layout col = lane&15, row = (lane>>4)*4 + reg ----
#pragma unroll
  for (int mi = 0; mi < 8; ++mi) {
#pragma unroll
    for (int ni = 0; ni < 4; ++ni) {
      const size_t col = b_row0 + wc * 64 + ni * 16 + llo;
      const size_t rbase = a_row0 + mi * 16 + lhi * 4;
#pragma unroll
      for (int j = 0; j < 4; ++j)
        C[(rbase + j) * (size_t)N + col] = acc[mi][ni][j];
    }
  }
}

// ---------- fallback: f32 tiled GEMM (only if ws_size too small) ----------
__global__ __launch_bounds__(256) void gemm_f32_fallback(const float* __restrict__ X,
                                                         const float* __restrict__ Km,
                                                         float* __restrict__ C,
                                                         int M, int N, int K) {
  __shared__ float As[64][16];
  __shared__ float Bs[16][65];
  const int nBN = N / 64;
  const int bm = blockIdx.x / nBN;
  const int bn = blockIdx.x % nBN;
  const int t = threadIdx.x;
  const int tx = t & 15, ty = t >> 4;
  float acc[4][4] = {};
  for (int kb = 0; kb < K; kb += 16) {
#pragma unroll
    for (int i = 0; i < 4; ++i) {
      int e = t + i * 256;
      int r = e >> 4, c = e & 15;
      As[r][c] = X[(size_t)(bm * 64 + r) * K + kb + c];
      int rk = e >> 6, cn = e & 63;
      float v = Km[(size_t)(kb + rk) * N + bn * 64 + cn];
      Bs[rk][cn] = (v >= 0.f) ? 1.f : -1.f;
    }
    __syncthreads();
#pragma unroll
    for (int kk = 0; kk < 16; ++kk) {
      float a[4], b[4];
#pragma unroll
      for (int r = 0; r < 4; ++r) a[r] = As[ty * 4 + r][kk];
#pragma unroll
      for (int c = 0; c < 4; ++c) b[c] = Bs[kk][tx * 4 + c];
#pragma unroll
      for (int r = 0; r < 4; ++r)
#pragma unroll
        for (int c = 0; c < 4; ++c) acc[r][c] += a[r] * b[c];
    }
    __syncthreads();
  }
#pragma unroll
  for (int r = 0; r < 4; ++r)
#pragma unroll
    for (int c = 0; c < 4; ++c)
      C[(size_t)(bm * 64 + ty * 4 + r) * N + bn * 64 + tx * 4 + c] = acc[r][c];
}

extern "C" void kernel_launch(void* const* d_in, const int* in_sizes, int n_in,
                              void* d_out, int out_size, void* d_ws, size_t ws_size,
                              hipStream_t stream) {
  const float* x = (const float*)d_in[0];
  const float* kern = (const float*)d_in[1];
  float* out = (float*)d_out;

  const int K = 4096;             // D_IN
  const int N = 4096;             // UNITS
  const int M = in_sizes[0] / K;  // 8192

  const size_t a_bytes = (size_t)M * K * 2;
  const size_t b_bytes = (size_t)N * K * 2;

  if (ws_size >= a_bytes + b_bytes && (M % 128) == 0 && (N % 256) == 0 && (K % 128) == 0) {
    unsigned short* A = (unsigned short*)d_ws;
    unsigned short* Bt = (unsigned short*)((char*)d_ws + a_bytes);
    convert_x_kernel<<<2048, 256, 0, stream>>>(x, A, (size_t)M * K);
    sign_transpose_kernel<<<dim3(K / 64, N / 64), 256, 0, stream>>>(kern, Bt, K, N);
    gemm_bf16_128x256<<<(M / 128) * (N / 256), 256, 0, stream>>>(A, Bt, out, M, N, K);
  } else {
    gemm_f32_fallback<<<(M / 64) * (N / 64), 256, 0, stream>>>(x, kern, out, M, N, K);
  }
}